// Round 1
// baseline (56.757 us; speedup 1.0000x reference)
//
#include <hip/hip_runtime.h>
#include <math.h>

#define NN 512
#define DD 128
#define TEMP_INV (1.0f / 0.07f)
#define EPSF 1e-8f

// ws float layout
#define WS_VN    0
#define WS_NORM  16
#define WS_SQN   (16 + NN)
#define WS_PROJ  (16 + 2*NN)
#define WS_PART  (16 + 3*NN)   // NN*4 floats: {ral_sum, ral_cnt, oal_sum, oal_cnt} per block

__global__ __launch_bounds__(128) void prep_kernel(
    const float* __restrict__ features,
    const float* __restrict__ v_prog,
    float* __restrict__ ws)
{
    __shared__ float s0[2], s1[2];
    const int i = blockIdx.x;
    const int t = threadIdx.x;
    if (i == NN) {
        float x = v_prog[t];
        float s = x * x;
        #pragma unroll
        for (int o = 32; o > 0; o >>= 1) s += __shfl_down(s, o);
        if ((t & 63) == 0) s0[t >> 6] = s;
        __syncthreads();
        if (t == 0) ws[WS_VN] = sqrtf(s0[0] + s0[1]) + EPSF;
        return;
    }
    const float* cfi = features + (i & 255) * (2 * DD) + (i >> 8) * DD;
    float x = cfi[t];
    float v = v_prog[t];
    float s = x * x;
    float p = x * v;
    #pragma unroll
    for (int o = 32; o > 0; o >>= 1) {
        s += __shfl_down(s, o);
        p += __shfl_down(p, o);
    }
    if ((t & 63) == 0) { s0[t >> 6] = s; s1[t >> 6] = p; }
    __syncthreads();
    if (t == 0) {
        float sq = s0[0] + s0[1];
        ws[WS_NORM + i] = sqrtf(sq);
        ws[WS_SQN  + i] = sq;
        ws[WS_PROJ + i] = s1[0] + s1[1];   // cf_i . v_prog (unnormalized)
    }
}

__global__ __launch_bounds__(256) void main_kernel(
    const float* __restrict__ features,
    const float* __restrict__ labels,
    float* __restrict__ ws)
{
    __shared__ float cfi_s[DD];
    __shared__ float sim_s[NN];
    __shared__ float es_s[NN];
    __shared__ float pd_s[NN];
    __shared__ float red_s[16];

    const int i = blockIdx.x;
    const int t = threadIdx.x;

    if (t < DD) {
        const float* cfi_g = features + (i & 255) * (2 * DD) + (i >> 8) * DD;
        cfi_s[t] = cfi_g[t];
    }
    __syncthreads();

    const float vn     = ws[WS_VN];
    const float pos_i  = labels[i & 255];
    const float sqn_i  = ws[WS_SQN + i];
    const float proj_i = ws[WS_PROJ + i];
    const float inv_ni = 1.0f / fmaxf(ws[WS_NORM + i], 1e-12f);

    float oal_sum = 0.0f, oal_cnt = 0.0f;

    // Phase 1: dots vs all k; fill sim/es/pd rows in LDS; OAL terms on the fly.
    #pragma unroll
    for (int kk = 0; kk < 2; ++kk) {
        const int k = t + kk * 256;
        const float4* cfk = (const float4*)(features + (k & 255) * (2 * DD) + (k >> 8) * DD);
        float d0 = 0.f, d1 = 0.f, d2 = 0.f, d3 = 0.f;
        #pragma unroll
        for (int q = 0; q < DD / 4; ++q) {
            float4 a = cfk[q];
            d0 += a.x * cfi_s[4*q+0];
            d1 += a.y * cfi_s[4*q+1];
            d2 += a.z * cfi_s[4*q+2];
            d3 += a.w * cfi_s[4*q+3];
        }
        const float dot = (d0 + d1) + (d2 + d3);
        const float sim = dot * inv_ni * (1.0f / fmaxf(ws[WS_NORM + k], 1e-12f)) * TEMP_INV;
        const float pos_k = labels[k & 255];
        const float pd = fabsf(pos_i - pos_k);
        sim_s[k] = sim;
        pd_s[k]  = pd;
        es_s[k]  = (k == i) ? 0.0f : __expf(sim);   // k==i excluded from denominators
        if (pos_i < pos_k) {
            float sqd  = fmaxf(sqn_i + ws[WS_SQN + k] - 2.0f * dot, 0.0f);
            float dist = sqrtf(fmaxf(sqd, 1e-24f));
            oal_sum += (ws[WS_PROJ + k] - proj_i) / (vn * fmaxf(dist, 1e-12f));
            oal_cnt += 1.0f;
        }
    }
    __syncthreads();

    // Phase 2: denominators via broadcast LDS scan.
    float ral_sum = 0.0f, ral_cnt = 0.0f;
    const float4* pd4 = (const float4*)pd_s;
    const float4* es4 = (const float4*)es_s;
    #pragma unroll
    for (int jj = 0; jj < 2; ++jj) {
        const int j = t + jj * 256;
        if (j == i) continue;
        const float thr = pd_s[j];
        float a0 = 0.f, a1 = 0.f, a2 = 0.f, a3 = 0.f;
        for (int q = 0; q < NN / 4; ++q) {
            float4 p = pd4[q];
            float4 e = es4[q];
            if (p.x >= thr) a0 += e.x;
            if (p.y >= thr) a1 += e.y;
            if (p.z >= thr) a2 += e.z;
            if (p.w >= thr) a3 += e.w;
        }
        const float denom = (a0 + a1) + (a2 + a3);
        if (denom > 0.0f) {
            float sw = 1.0f / (1.0f + __expf(-thr));           // sigmoid(pd)
            ral_sum += (__logf(denom + EPSF) - sim_s[j]) * sw; // -log(es/(denom+eps))
            ral_cnt += 1.0f;
        }
    }

    // Block reduce 4 quantities.
    #pragma unroll
    for (int o = 32; o > 0; o >>= 1) {
        ral_sum += __shfl_down(ral_sum, o);
        ral_cnt += __shfl_down(ral_cnt, o);
        oal_sum += __shfl_down(oal_sum, o);
        oal_cnt += __shfl_down(oal_cnt, o);
    }
    const int wid = t >> 6;
    if ((t & 63) == 0) {
        red_s[wid*4+0] = ral_sum; red_s[wid*4+1] = ral_cnt;
        red_s[wid*4+2] = oal_sum; red_s[wid*4+3] = oal_cnt;
    }
    __syncthreads();
    if (t == 0) {
        float rs = 0.f, rc = 0.f, os = 0.f, oc = 0.f;
        #pragma unroll
        for (int w = 0; w < 4; ++w) {
            rs += red_s[w*4+0]; rc += red_s[w*4+1];
            os += red_s[w*4+2]; oc += red_s[w*4+3];
        }
        float* part = ws + WS_PART + i * 4;
        part[0] = rs; part[1] = rc; part[2] = os; part[3] = oc;
    }
}

__global__ __launch_bounds__(256) void final_kernel(
    const float* __restrict__ ws, float* __restrict__ out)
{
    __shared__ double red_s[16];
    const int t = threadIdx.x;
    double rs = 0.0, rc = 0.0, os = 0.0, oc = 0.0;
    for (int b = t; b < NN; b += 256) {
        const float* p = ws + WS_PART + b * 4;
        rs += (double)p[0]; rc += (double)p[1];
        os += (double)p[2]; oc += (double)p[3];
    }
    #pragma unroll
    for (int o = 32; o > 0; o >>= 1) {
        rs += __shfl_down(rs, o);
        rc += __shfl_down(rc, o);
        os += __shfl_down(os, o);
        oc += __shfl_down(oc, o);
    }
    if ((t & 63) == 0) {
        int w = t >> 6;
        red_s[w*4+0] = rs; red_s[w*4+1] = rc;
        red_s[w*4+2] = os; red_s[w*4+3] = oc;
    }
    __syncthreads();
    if (t == 0) {
        double RS = 0, RC = 0, OS = 0, OC = 0;
        for (int w = 0; w < 4; ++w) {
            RS += red_s[w*4+0]; RC += red_s[w*4+1];
            OS += red_s[w*4+2]; OC += red_s[w*4+3];
        }
        double ral = (RC > 0.0) ? RS / RC : 0.0;
        double oal = (OC > 0.0) ? -(OS / OC) : 0.0;
        out[0] = (float)(ral + oal);
    }
}

extern "C" void kernel_launch(void* const* d_in, const int* in_sizes, int n_in,
                              void* d_out, int out_size, void* d_ws, size_t ws_size,
                              hipStream_t stream) {
    const float* features = (const float*)d_in[0];
    const float* labels   = (const float*)d_in[1];
    const float* v_prog   = (const float*)d_in[2];
    float* ws  = (float*)d_ws;
    float* out = (float*)d_out;

    hipLaunchKernelGGL(prep_kernel,  dim3(NN + 1), dim3(DD),  0, stream, features, v_prog, ws);
    hipLaunchKernelGGL(main_kernel,  dim3(NN),     dim3(256), 0, stream, features, labels, ws);
    hipLaunchKernelGGL(final_kernel, dim3(1),      dim3(256), 0, stream, ws, out);
}

// Round 2
// 50.878 us; speedup vs baseline: 1.1156x; 1.1156x over previous
//
#include <hip/hip_runtime.h>
#include <math.h>

#define NN 512
#define DD 128
#define TEMP_INV (1.0f / 0.07f)
#define EPSF 1e-8f

// ws float layout (requires ws_size >= ~2.2 MB)
#define WS_VN       0
#define WS_NORM     16
#define WS_SQN      (16 + NN)
#define WS_PROJ     (16 + 2*NN)
#define WS_PART_OAL (16 + 3*NN)              // NN*2 floats {oal_sum, oal_cnt}
#define WS_PART_RAL (16 + 5*NN)              // NN*2 floats {ral_sum, ral_cnt}
#define WS_PE       8192                      // float2 pe[NN][NN] = {pd, es}, 2 MB

__global__ __launch_bounds__(128) void prep_kernel(
    const float* __restrict__ features,
    const float* __restrict__ v_prog,
    float* __restrict__ ws)
{
    __shared__ float s0[2], s1[2];
    const int i = blockIdx.x;
    const int t = threadIdx.x;
    if (i == NN) {
        float x = v_prog[t];
        float s = x * x;
        #pragma unroll
        for (int o = 32; o > 0; o >>= 1) s += __shfl_down(s, o);
        if ((t & 63) == 0) s0[t >> 6] = s;
        __syncthreads();
        if (t == 0) ws[WS_VN] = sqrtf(s0[0] + s0[1]) + EPSF;
        return;
    }
    const float* cfi = features + (i & 255) * (2 * DD) + (i >> 8) * DD;
    float x = cfi[t];
    float v = v_prog[t];
    float s = x * x;
    float p = x * v;
    #pragma unroll
    for (int o = 32; o > 0; o >>= 1) {
        s += __shfl_down(s, o);
        p += __shfl_down(p, o);
    }
    if ((t & 63) == 0) { s0[t >> 6] = s; s1[t >> 6] = p; }
    __syncthreads();
    if (t == 0) {
        float sq = s0[0] + s0[1];
        ws[WS_NORM + i] = sqrtf(sq);
        ws[WS_SQN  + i] = sq;
        ws[WS_PROJ + i] = s1[0] + s1[1];   // cf_i . v_prog (unnormalized)
    }
}

// One block per row i: dots vs all k -> write {pd, es} row to global ws;
// OAL terms on the fly.
__global__ __launch_bounds__(256) void sim_kernel(
    const float* __restrict__ features,
    const float* __restrict__ labels,
    float* __restrict__ ws)
{
    __shared__ float cfi_s[DD];
    __shared__ float red_s[8];
    const int i = blockIdx.x;
    const int t = threadIdx.x;

    if (t < DD) {
        cfi_s[t] = features[(i & 255) * (2 * DD) + (i >> 8) * DD + t];
    }
    __syncthreads();

    const float vn     = ws[WS_VN];
    const float pos_i  = labels[i & 255];
    const float sqn_i  = ws[WS_SQN + i];
    const float proj_i = ws[WS_PROJ + i];
    const float inv_ni = 1.0f / fmaxf(ws[WS_NORM + i], 1e-12f);
    float2* __restrict__ pe = (float2*)(ws + WS_PE) + (size_t)i * NN;

    float oal_sum = 0.0f, oal_cnt = 0.0f;

    #pragma unroll
    for (int kk = 0; kk < 2; ++kk) {
        const int k = t + kk * 256;
        const float4* cfk = (const float4*)(features + (k & 255) * (2 * DD) + (k >> 8) * DD);
        float d0 = 0.f, d1 = 0.f, d2 = 0.f, d3 = 0.f;
        #pragma unroll
        for (int q = 0; q < DD / 4; ++q) {
            float4 a = cfk[q];
            d0 += a.x * cfi_s[4*q+0];
            d1 += a.y * cfi_s[4*q+1];
            d2 += a.z * cfi_s[4*q+2];
            d3 += a.w * cfi_s[4*q+3];
        }
        const float dot = (d0 + d1) + (d2 + d3);
        const float sim = dot * inv_ni * (1.0f / fmaxf(ws[WS_NORM + k], 1e-12f)) * TEMP_INV;
        const float pos_k = labels[k & 255];
        const float pd = fabsf(pos_i - pos_k);
        const float es = (k == i) ? 0.0f : __expf(sim);  // k==i excluded from denominators
        pe[k] = make_float2(pd, es);
        if (pos_i < pos_k) {
            float sqd  = fmaxf(sqn_i + ws[WS_SQN + k] - 2.0f * dot, 0.0f);
            float dist = sqrtf(fmaxf(sqd, 1e-24f));
            oal_sum += (ws[WS_PROJ + k] - proj_i) / (vn * fmaxf(dist, 1e-12f));
            oal_cnt += 1.0f;
        }
    }

    #pragma unroll
    for (int o = 32; o > 0; o >>= 1) {
        oal_sum += __shfl_down(oal_sum, o);
        oal_cnt += __shfl_down(oal_cnt, o);
    }
    const int wid = t >> 6;
    if ((t & 63) == 0) { red_s[wid*2+0] = oal_sum; red_s[wid*2+1] = oal_cnt; }
    __syncthreads();
    if (t == 0) {
        float os = 0.f, oc = 0.f;
        #pragma unroll
        for (int w = 0; w < 4; ++w) { os += red_s[w*2+0]; oc += red_s[w*2+1]; }
        ws[WS_PART_OAL + i*2 + 0] = os;
        ws[WS_PART_OAL + i*2 + 1] = oc;
    }
}

// One block (1024 threads, 16 waves) per row i. Thread t handles j = t&511
// over k-half (t>>9). The k-scan reads pe[i][*] with WAVE-UNIFORM addresses
// -> scalar/uniform loads, no LDS latency chain.
__global__ __launch_bounds__(1024) void ral_kernel(
    const float* __restrict__ ws_c,
    float* __restrict__ ws)
{
    __shared__ float comb[1024];
    __shared__ float red_s[32];

    const int i = blockIdx.x;
    const int t = threadIdx.x;
    const int jj = t & (NN - 1);
    const int half = t >> 9;                       // wave-uniform in reality

    const float2* __restrict__ pe2 = (const float2*)(ws_c + WS_PE) + (size_t)i * NN;
    const float4* __restrict__ pe4 = (const float4*)pe2;   // 2 k per float4

    const float2 pj = pe2[jj];
    const float thr = pj.x;                        // pd[i][j]
    const float esj = pj.y;                        // exp(sim[i][j]) (0 if j==i)

    // scan 256 k = 128 float4, base forced uniform for scalar loads
    const int q0 = __builtin_amdgcn_readfirstlane(half * (NN / 4));
    float a0 = 0.f, a1 = 0.f, a2 = 0.f, a3 = 0.f;
    #pragma unroll 8
    for (int q = 0; q < NN / 4; q += 2) {
        float4 v0 = pe4[q0 + q];
        float4 v1 = pe4[q0 + q + 1];
        if (v0.x >= thr) a0 += v0.y;
        if (v0.z >= thr) a1 += v0.w;
        if (v1.x >= thr) a2 += v1.y;
        if (v1.z >= thr) a3 += v1.w;
    }
    comb[t] = (a0 + a1) + (a2 + a3);
    __syncthreads();

    float ral_sum = 0.0f, ral_cnt = 0.0f;
    if (t < NN) {
        const float denom = comb[t] + comb[t + NN];
        if (jj != i && denom > 0.0f) {
            const float sw = 1.0f / (1.0f + __expf(-thr));          // sigmoid(pd)
            ral_sum = (__logf(denom + EPSF) - __logf(esj)) * sw;    // -log(es/(denom+eps))
            ral_cnt = 1.0f;
        }
    }

    #pragma unroll
    for (int o = 32; o > 0; o >>= 1) {
        ral_sum += __shfl_down(ral_sum, o);
        ral_cnt += __shfl_down(ral_cnt, o);
    }
    const int wid = t >> 6;
    if ((t & 63) == 0) { red_s[wid*2+0] = ral_sum; red_s[wid*2+1] = ral_cnt; }
    __syncthreads();
    if (t == 0) {
        float rs = 0.f, rc = 0.f;
        #pragma unroll
        for (int w = 0; w < 16; ++w) { rs += red_s[w*2+0]; rc += red_s[w*2+1]; }
        ws[WS_PART_RAL + i*2 + 0] = rs;
        ws[WS_PART_RAL + i*2 + 1] = rc;
    }
}

__global__ __launch_bounds__(256) void final_kernel(
    const float* __restrict__ ws, float* __restrict__ out)
{
    __shared__ double red_s[16];
    const int t = threadIdx.x;
    double rs = 0.0, rc = 0.0, os = 0.0, oc = 0.0;
    for (int b = t; b < NN; b += 256) {
        rs += (double)ws[WS_PART_RAL + b*2 + 0];
        rc += (double)ws[WS_PART_RAL + b*2 + 1];
        os += (double)ws[WS_PART_OAL + b*2 + 0];
        oc += (double)ws[WS_PART_OAL + b*2 + 1];
    }
    #pragma unroll
    for (int o = 32; o > 0; o >>= 1) {
        rs += __shfl_down(rs, o);
        rc += __shfl_down(rc, o);
        os += __shfl_down(os, o);
        oc += __shfl_down(oc, o);
    }
    if ((t & 63) == 0) {
        int w = t >> 6;
        red_s[w*4+0] = rs; red_s[w*4+1] = rc;
        red_s[w*4+2] = os; red_s[w*4+3] = oc;
    }
    __syncthreads();
    if (t == 0) {
        double RS = 0, RC = 0, OS = 0, OC = 0;
        for (int w = 0; w < 4; ++w) {
            RS += red_s[w*4+0]; RC += red_s[w*4+1];
            OS += red_s[w*4+2]; OC += red_s[w*4+3];
        }
        double ral = (RC > 0.0) ? RS / RC : 0.0;
        double oal = (OC > 0.0) ? -(OS / OC) : 0.0;
        out[0] = (float)(ral + oal);
    }
}

extern "C" void kernel_launch(void* const* d_in, const int* in_sizes, int n_in,
                              void* d_out, int out_size, void* d_ws, size_t ws_size,
                              hipStream_t stream) {
    const float* features = (const float*)d_in[0];
    const float* labels   = (const float*)d_in[1];
    const float* v_prog   = (const float*)d_in[2];
    float* ws  = (float*)d_ws;
    float* out = (float*)d_out;

    hipLaunchKernelGGL(prep_kernel,  dim3(NN + 1), dim3(DD),   0, stream, features, v_prog, ws);
    hipLaunchKernelGGL(sim_kernel,   dim3(NN),     dim3(256),  0, stream, features, labels, ws);
    hipLaunchKernelGGL(ral_kernel,   dim3(NN),     dim3(1024), 0, stream, ws, ws);
    hipLaunchKernelGGL(final_kernel, dim3(1),      dim3(256),  0, stream, ws, out);
}

// Round 3
// 43.292 us; speedup vs baseline: 1.3110x; 1.1752x over previous
//
#include <hip/hip_runtime.h>
#include <math.h>

#define NN 512
#define DD 128
#define TEMP_INV (1.0f / 0.07f)
#define EPSF 1e-8f

// ws float layout (~20 KB used)
#define WS_VN       0
#define WS_NORM     16
#define WS_SQN      (16 + NN)
#define WS_PROJ     (16 + 2*NN)
#define WS_PART_OAL (16 + 3*NN)   // NN*2 floats {oal_sum, oal_cnt}
#define WS_PART_RAL (16 + 5*NN)   // NN*2 floats {ral_sum, ral_cnt}
#define WS_SV       4096          // float[NN]: sorted pos values (ascending)
#define WS_RK       (4096 + NN)   // int[NN]: rank of k in sorted order

// blocks 0..511: per-row norm/sqn/proj. block 512: ||v_prog||.
// blocks 513..516: counting ranks of the 512 positions (128 k's each).
__global__ __launch_bounds__(128) void prep_kernel(
    const float* __restrict__ features,
    const float* __restrict__ labels,
    const float* __restrict__ v_prog,
    float* __restrict__ ws)
{
    const int b = blockIdx.x;
    const int t = threadIdx.x;
    if (b < NN) {
        __shared__ float s0[2], s1[2];
        const int i = b;
        const float* cfi = features + (i & 255) * (2 * DD) + (i >> 8) * DD;
        float x = cfi[t];
        float v = v_prog[t];
        float s = x * x, p = x * v;
        #pragma unroll
        for (int o = 32; o > 0; o >>= 1) { s += __shfl_down(s, o); p += __shfl_down(p, o); }
        if ((t & 63) == 0) { s0[t >> 6] = s; s1[t >> 6] = p; }
        __syncthreads();
        if (t == 0) {
            float sq = s0[0] + s0[1];
            ws[WS_NORM + i] = sqrtf(sq);
            ws[WS_SQN  + i] = sq;
            ws[WS_PROJ + i] = s1[0] + s1[1];
        }
    } else if (b == NN) {
        __shared__ float s0[2];
        float x = v_prog[t];
        float s = x * x;
        #pragma unroll
        for (int o = 32; o > 0; o >>= 1) s += __shfl_down(s, o);
        if ((t & 63) == 0) s0[t >> 6] = s;
        __syncthreads();
        if (t == 0) ws[WS_VN] = sqrtf(s0[0] + s0[1]) + EPSF;
    } else {
        __shared__ float pos_s[NN];
        for (int m = t; m < NN; m += 128) pos_s[m] = labels[m & 255];
        __syncthreads();
        const int k = (b - (NN + 1)) * 128 + t;
        const float pk = pos_s[k];
        int r = 0;
        for (int m = 0; m < NN; ++m) {
            float pm = pos_s[m];                       // uniform addr -> LDS broadcast
            r += (pm < pk) || (pm == pk && m < k);     // stable rank
        }
        ws[WS_SV + r] = pk;
        ((int*)ws)[WS_RK + k] = r;
    }
}

// One block (512 threads) per row i. Thread t is both k=t (sim/es/OAL) and
// j=t (RAL term). Denominators via sorted-order prefix sums + binary search.
__global__ __launch_bounds__(512) void main_kernel(
    const float* __restrict__ features,
    const float* __restrict__ labels,
    float* __restrict__ ws)
{
    __shared__ float cfi_s[DD];
    __shared__ float sv_s[NN];
    __shared__ float esS[NN];     // scattered es, then inclusive prefix scan (in place)
    __shared__ float wtot[8];
    __shared__ float red_s[32];

    const int i = blockIdx.x;
    const int t = threadIdx.x;

    if (t < DD) cfi_s[t] = features[(i & 255) * (2 * DD) + (i >> 8) * DD + t];
    sv_s[t] = ws[WS_SV + t];
    const int rk = ((const int*)ws)[WS_RK + t];
    __syncthreads();

    const float vn     = ws[WS_VN];
    const float pos_i  = labels[i & 255];
    const float sqn_i  = ws[WS_SQN + i];
    const float proj_i = ws[WS_PROJ + i];
    const float inv_ni = 1.0f / fmaxf(ws[WS_NORM + i], 1e-12f);

    // ---- phase 1: k = t -> dot, sim, es (scatter to sorted slot), OAL term
    const int k = t;
    const float4* cfk = (const float4*)(features + (k & 255) * (2 * DD) + (k >> 8) * DD);
    float d0 = 0.f, d1 = 0.f, d2 = 0.f, d3 = 0.f;
    #pragma unroll
    for (int q = 0; q < DD / 4; ++q) {
        float4 a = cfk[q];
        d0 += a.x * cfi_s[4*q+0];
        d1 += a.y * cfi_s[4*q+1];
        d2 += a.z * cfi_s[4*q+2];
        d3 += a.w * cfi_s[4*q+3];
    }
    const float dot = (d0 + d1) + (d2 + d3);
    const float sim = dot * inv_ni * (1.0f / fmaxf(ws[WS_NORM + k], 1e-12f)) * TEMP_INV;
    const float pos_k = labels[k & 255];
    const float es = (k == i) ? 0.0f : __expf(sim);   // k==i excluded everywhere
    esS[rk] = es;

    float oal_sum = 0.f, oal_cnt = 0.f;
    if (pos_i < pos_k) {
        float sqd  = fmaxf(sqn_i + ws[WS_SQN + k] - 2.0f * dot, 0.0f);
        float dist = sqrtf(fmaxf(sqd, 1e-24f));
        oal_sum = (ws[WS_PROJ + k] - proj_i) / (vn * fmaxf(dist, 1e-12f));
        oal_cnt = 1.0f;
    }
    __syncthreads();

    // ---- inclusive prefix scan of esS[512]
    float v = esS[t];
    float s = v;
    #pragma unroll
    for (int off = 1; off < 64; off <<= 1) {
        float u = __shfl_up(s, off);
        if ((t & 63) >= off) s += u;
    }
    const int wid = t >> 6;
    if ((t & 63) == 63) wtot[wid] = s;
    __syncthreads();
    float woff = 0.f;
    for (int w = 0; w < wid; ++w) woff += wtot[w];   // wid is wave-uniform
    esS[t] = s + woff;
    __syncthreads();
    const float total = esS[NN - 1];

    // ---- phase 2: j = t -> denom via interval [lo,hi) of {k: |p_i-p_k| < thr}
    const float thr = fabsf(pos_i - pos_k);          // pos_j == pos_k (j==k==t)

    int R = 0;                                        // first r with sv[r] >= pos_i
    #pragma unroll
    for (int step = 256; step > 0; step >>= 1)
        if (R + step <= NN && sv_s[R + step - 1] < pos_i) R += step;
    int lo = 0;                                       // first r in [0,R) with f < thr
    #pragma unroll
    for (int step = 256; step > 0; step >>= 1)
        if (lo + step <= R && !(fabsf(pos_i - sv_s[lo + step - 1]) < thr)) lo += step;
    int hi = R;                                       // first r in [R,NN) with f >= thr
    #pragma unroll
    for (int step = 256; step > 0; step >>= 1)
        if (hi + step <= NN && (fabsf(pos_i - sv_s[hi + step - 1]) < thr)) hi += step;

    const float pe_lo = (lo > 0) ? esS[lo - 1] : 0.0f;
    const float pe_hi = (hi > 0) ? esS[hi - 1] : 0.0f;
    float ral_sum = 0.f, ral_cnt = 0.f;
    if (t != i) {
        // denom >= es_j mathematically (k=j is in the masked set); clamp guards
        // scan rounding so the reference's denom>0 branch is always taken.
        float denom = fmaxf(pe_lo + (total - pe_hi), es);
        const float sw = 1.0f / (1.0f + __expf(-thr));          // sigmoid(pd)
        ral_sum = (__logf(denom + EPSF) - sim) * sw;            // -log(es/(denom+eps))
        ral_cnt = 1.0f;
    }

    // ---- block reduce {ral_sum, ral_cnt, oal_sum, oal_cnt}
    #pragma unroll
    for (int o = 32; o > 0; o >>= 1) {
        ral_sum += __shfl_down(ral_sum, o);
        ral_cnt += __shfl_down(ral_cnt, o);
        oal_sum += __shfl_down(oal_sum, o);
        oal_cnt += __shfl_down(oal_cnt, o);
    }
    if ((t & 63) == 0) {
        red_s[wid*4+0] = ral_sum; red_s[wid*4+1] = ral_cnt;
        red_s[wid*4+2] = oal_sum; red_s[wid*4+3] = oal_cnt;
    }
    __syncthreads();
    if (t == 0) {
        float rs = 0.f, rc = 0.f, os = 0.f, oc = 0.f;
        #pragma unroll
        for (int w = 0; w < 8; ++w) {
            rs += red_s[w*4+0]; rc += red_s[w*4+1];
            os += red_s[w*4+2]; oc += red_s[w*4+3];
        }
        ws[WS_PART_RAL + i*2 + 0] = rs;
        ws[WS_PART_RAL + i*2 + 1] = rc;
        ws[WS_PART_OAL + i*2 + 0] = os;
        ws[WS_PART_OAL + i*2 + 1] = oc;
    }
}

__global__ __launch_bounds__(256) void final_kernel(
    const float* __restrict__ ws, float* __restrict__ out)
{
    __shared__ double red_s[16];
    const int t = threadIdx.x;
    double rs = 0.0, rc = 0.0, os = 0.0, oc = 0.0;
    for (int b = t; b < NN; b += 256) {
        rs += (double)ws[WS_PART_RAL + b*2 + 0];
        rc += (double)ws[WS_PART_RAL + b*2 + 1];
        os += (double)ws[WS_PART_OAL + b*2 + 0];
        oc += (double)ws[WS_PART_OAL + b*2 + 1];
    }
    #pragma unroll
    for (int o = 32; o > 0; o >>= 1) {
        rs += __shfl_down(rs, o);
        rc += __shfl_down(rc, o);
        os += __shfl_down(os, o);
        oc += __shfl_down(oc, o);
    }
    if ((t & 63) == 0) {
        int w = t >> 6;
        red_s[w*4+0] = rs; red_s[w*4+1] = rc;
        red_s[w*4+2] = os; red_s[w*4+3] = oc;
    }
    __syncthreads();
    if (t == 0) {
        double RS = 0, RC = 0, OS = 0, OC = 0;
        for (int w = 0; w < 4; ++w) {
            RS += red_s[w*4+0]; RC += red_s[w*4+1];
            OS += red_s[w*4+2]; OC += red_s[w*4+3];
        }
        double ral = (RC > 0.0) ? RS / RC : 0.0;
        double oal = (OC > 0.0) ? -(OS / OC) : 0.0;
        out[0] = (float)(ral + oal);
    }
}

extern "C" void kernel_launch(void* const* d_in, const int* in_sizes, int n_in,
                              void* d_out, int out_size, void* d_ws, size_t ws_size,
                              hipStream_t stream) {
    const float* features = (const float*)d_in[0];
    const float* labels   = (const float*)d_in[1];
    const float* v_prog   = (const float*)d_in[2];
    float* ws  = (float*)d_ws;
    float* out = (float*)d_out;

    hipLaunchKernelGGL(prep_kernel,  dim3(NN + 5), dim3(128), 0, stream, features, labels, v_prog, ws);
    hipLaunchKernelGGL(main_kernel,  dim3(NN),     dim3(512), 0, stream, features, labels, ws);
    hipLaunchKernelGGL(final_kernel, dim3(1),      dim3(256), 0, stream, ws, out);
}